// Round 1
// 468.244 us; speedup vs baseline: 1.0017x; 1.0017x over previous
//
#include <hip/hip_runtime.h>

// Sizes
#define BB 16
#define IC 8
#define OC 8
#define NV 3
#define M1 16
#define M2 16
#define HH 256
#define WW 256
#define NIMG_IN  (BB*IC*NV)        // 384
#define NIMG_OUT (BB*OC*NV)        // 384
#define NROWS    (IC*OC*NV*M1*M2)  // 49152
#define TWO_PI 6.28318530717958647692f

// ---------------------------------------------------------------------------
// K1a: row DFT. grid = 768. blocks [0,384) = kx 0..8, [384,768) = kx 9..16
// (384 apart -> same XCD -> shared L2 for the image double-read).
// block 256 = (col4 0..63, hq 0..3). Each thread: 4-row-deep prefetched
// float4 x-loads over its 64-h slice, 9 kx accumulators in regs, twiddles
// via wave-uniform LDS broadcast. 2-round LDS reduction over hq.
// y[img][kx][w] = sum_h e^{-2pi i kx h/256} x[h][w], kx in 0..16.
// ---------------------------------------------------------------------------
__global__ __launch_bounds__(256, 3) void k1a_rowdft(const float* __restrict__ x,
                                                     float2* __restrict__ y) {
  __shared__ float2 tbl[256];
  __shared__ float red[2][64][73];  // 37.4 KB, stride 73 (odd) -> conflict-free
  const int tid = threadIdx.x;
  const int bid = blockIdx.x;
  const int half = (bid >= 384) ? 1 : 0;
  const int img = bid - half * 384;
  const int kbase = half ? 9 : 0;
  const int kcount = half ? 8 : 9;
  {
    float s, c;
    sincosf((float)tid * (TWO_PI / 256.0f), &s, &c);
    tbl[tid] = make_float2(c, s);
  }
  __syncthreads();

  const int col4 = tid & 63;
  const int hq = tid >> 6;
  const int hbase = hq * 64;
  const float4* xp = (const float4*)(x + (size_t)img * 65536) + col4;

  float ar[9][4], ai[9][4];
#pragma unroll
  for (int j = 0; j < 9; j++)
#pragma unroll
    for (int c = 0; c < 4; c++) { ar[j][c] = 0.0f; ai[j][c] = 0.0f; }

  // 4-deep rotating prefetch: 4 outstanding VMEM per wave, FMA block shadows
  // the latency of the next quad's loads.
  float4 c0 = xp[(size_t)(hbase + 0) * 64];
  float4 c1 = xp[(size_t)(hbase + 1) * 64];
  float4 c2 = xp[(size_t)(hbase + 2) * 64];
  float4 c3 = xp[(size_t)(hbase + 3) * 64];

  for (int hi = 0; hi < 64; hi += 4) {
    const int hn = (hbase + hi + 4) & 255;  // wraps in-image; dead on last iter
    float4 n0 = xp[(size_t)(hn + 0) * 64];
    float4 n1 = xp[(size_t)(hn + 1) * 64];
    float4 n2 = xp[(size_t)(hn + 2) * 64];
    float4 n3 = xp[(size_t)(hn + 3) * 64];

    const int h = hbase + hi;
    // twiddle exponents: m_j(row) = (kbase+j)*row mod 256; per-row chains
    int m0 = (kbase * h) & 255;
    int m1 = (m0 + kbase) & 255;
    int m2 = (m1 + kbase) & 255;
    int m3 = (m2 + kbase) & 255;
#pragma unroll
    for (int j = 0; j < 9; j++) {
      float2 e0 = tbl[m0];  m0 = (m0 + h) & 255;        // wave-uniform -> broadcast
      float2 e1 = tbl[m1];  m1 = (m1 + h + 1) & 255;
      float2 e2 = tbl[m2];  m2 = (m2 + h + 2) & 255;
      float2 e3 = tbl[m3];  m3 = (m3 + h + 3) & 255;

      ar[j][0] = fmaf(e0.x, c0.x, ar[j][0]);  ai[j][0] = fmaf(-e0.y, c0.x, ai[j][0]);
      ar[j][1] = fmaf(e0.x, c0.y, ar[j][1]);  ai[j][1] = fmaf(-e0.y, c0.y, ai[j][1]);
      ar[j][2] = fmaf(e0.x, c0.z, ar[j][2]);  ai[j][2] = fmaf(-e0.y, c0.z, ai[j][2]);
      ar[j][3] = fmaf(e0.x, c0.w, ar[j][3]);  ai[j][3] = fmaf(-e0.y, c0.w, ai[j][3]);

      ar[j][0] = fmaf(e1.x, c1.x, ar[j][0]);  ai[j][0] = fmaf(-e1.y, c1.x, ai[j][0]);
      ar[j][1] = fmaf(e1.x, c1.y, ar[j][1]);  ai[j][1] = fmaf(-e1.y, c1.y, ai[j][1]);
      ar[j][2] = fmaf(e1.x, c1.z, ar[j][2]);  ai[j][2] = fmaf(-e1.y, c1.z, ai[j][2]);
      ar[j][3] = fmaf(e1.x, c1.w, ar[j][3]);  ai[j][3] = fmaf(-e1.y, c1.w, ai[j][3]);

      ar[j][0] = fmaf(e2.x, c2.x, ar[j][0]);  ai[j][0] = fmaf(-e2.y, c2.x, ai[j][0]);
      ar[j][1] = fmaf(e2.x, c2.y, ar[j][1]);  ai[j][1] = fmaf(-e2.y, c2.y, ai[j][1]);
      ar[j][2] = fmaf(e2.x, c2.z, ar[j][2]);  ai[j][2] = fmaf(-e2.y, c2.z, ai[j][2]);
      ar[j][3] = fmaf(e2.x, c2.w, ar[j][3]);  ai[j][3] = fmaf(-e2.y, c2.w, ai[j][3]);

      ar[j][0] = fmaf(e3.x, c3.x, ar[j][0]);  ai[j][0] = fmaf(-e3.y, c3.x, ai[j][0]);
      ar[j][1] = fmaf(e3.x, c3.y, ar[j][1]);  ai[j][1] = fmaf(-e3.y, c3.y, ai[j][1]);
      ar[j][2] = fmaf(e3.x, c3.z, ar[j][2]);  ai[j][2] = fmaf(-e3.y, c3.z, ai[j][2]);
      ar[j][3] = fmaf(e3.x, c3.w, ar[j][3]);  ai[j][3] = fmaf(-e3.y, c3.w, ai[j][3]);
    }
    c0 = n0; c1 = n1; c2 = n2; c3 = n3;
  }

  // reduce over hq (4 partials) in two rounds
  if (hq >= 2) {
    float* p = red[hq - 2][col4];
#pragma unroll
    for (int j = 0; j < 9; j++)
#pragma unroll
      for (int c = 0; c < 4; c++) { p[j * 8 + c * 2] = ar[j][c]; p[j * 8 + c * 2 + 1] = ai[j][c]; }
  }
  __syncthreads();
  if (hq < 2) {
    const float* p = red[hq][col4];
#pragma unroll
    for (int j = 0; j < 9; j++)
#pragma unroll
      for (int c = 0; c < 4; c++) { ar[j][c] += p[j * 8 + c * 2]; ai[j][c] += p[j * 8 + c * 2 + 1]; }
  }
  __syncthreads();
  if (hq == 1) {
    float* p = red[0][col4];
#pragma unroll
    for (int j = 0; j < 9; j++)
#pragma unroll
      for (int c = 0; c < 4; c++) { p[j * 8 + c * 2] = ar[j][c]; p[j * 8 + c * 2 + 1] = ai[j][c]; }
  }
  __syncthreads();
  if (hq == 0) {
    const float* p = red[0][col4];
    float2* yo = y + (size_t)img * 4352;
    for (int j = 0; j < kcount; j++) {
#pragma unroll
      for (int c = 0; c < 4; c++) {
        float rr = ar[j][c] + p[j * 8 + c * 2];
        float ii = ai[j][c] + p[j * 8 + c * 2 + 1];
        yo[(kbase + j) * 256 + col4 * 4 + c] = make_float2(rr, ii);
      }
    }
  }
}

// ---------------------------------------------------------------------------
// K1b: column DFT over retained ky modes. grid = 384 (img).
// ---------------------------------------------------------------------------
__global__ __launch_bounds__(256) void k1b_coldft(const float2* __restrict__ y,
                                                  float2* __restrict__ Xf) {
  __shared__ float2 tbl[256];
  __shared__ float2 yb[17 * 257];
  const int tid = threadIdx.x;
  const int img = blockIdx.x;
  {
    float s, c;
    sincosf((float)tid * (TWO_PI / 256.0f), &s, &c);
    tbl[tid] = make_float2(c, s);
  }
  const float2* yg = y + (size_t)img * 4352;
  for (int n = tid; n < 4352; n += 256) {
    int kx = n >> 8, w = n & 255;
    yb[kx * 257 + w] = yg[n];
  }
  __syncthreads();

  float2* XfImg = Xf + (size_t)img * 512;
  for (int n = tid; n < 512; n += 256) {
    int row = n >> 4, ky = n & 15;
    int kxl = (row < 16) ? row : (32 - row);
    float sgn = (row < 16) ? 1.0f : -1.0f;
    float Xr = 0.0f, Xi = 0.0f;
    int m = 0;
    for (int w2 = 0; w2 < 256; w2++) {
      float2 yv = yb[kxl * 257 + w2];
      float2 e = tbl[m];
      m = (m + ky) & 255;
      float yy = yv.y * sgn;
      Xr += yv.x * e.x + yy * e.y;
      Xi += yy * e.x - yv.x * e.y;
    }
    XfImg[n] = make_float2(Xr, Xi);
  }
}

// ---------------------------------------------------------------------------
// K2: tw[b][row] = sum_t t[b][t] * w[row][t].  grid = 3072 (16 rows/block).
// Coalesced float4 staging of w tiles into LDS (XOR swizzle, conflict-free),
// thread = (b, r) computes via broadcast t + swizzled w reads.
// Two passes: (w1r,w1i) then (w2r,w2i); LDS = 16.6 + 32 KB.
// ---------------------------------------------------------------------------
__global__ __launch_bounds__(256) void k2_tw(const float* __restrict__ t,
                                             const float* __restrict__ w1r,
                                             const float* __restrict__ w1i,
                                             const float* __restrict__ w2r,
                                             const float* __restrict__ w2i,
                                             float2* __restrict__ tw1,
                                             float2* __restrict__ tw2) {
  __shared__ float tL[16 * 260];          // [b][260], padded (65 float4 pitch)
  __shared__ float4 wA[2][16 * 64];       // [arr][row][t4 ^ (row&7)]
  const int tid = threadIdx.x;
  const int row0 = blockIdx.x * 16;
  const int b = tid >> 4;
  const int r = tid & 15;
  const int c = r & 7;

  // stage t (once): 1024 float4, coalesced
  {
    const float4* tg = (const float4*)t;
    float4* ts = (float4*)tL;
    for (int n = tid; n < 1024; n += 256) ts[(n >> 6) * 65 + (n & 63)] = tg[n];
  }

  float o1r, o1i, o2r, o2i;
  const float4* tb4 = (const float4*)tL + b * 65;

  for (int pass = 0; pass < 2; pass++) {
    const float* wa = pass ? w2r : w1r;
    const float* wb = pass ? w2i : w1i;
    // stage w pair, coalesced with XOR swizzle
    const float4* ga = (const float4*)(wa + (size_t)row0 * 256);
    const float4* gb = (const float4*)(wb + (size_t)row0 * 256);
    for (int n = tid; n < 1024; n += 256) {
      int rr = n >> 6, t4 = n & 63;
      int sidx = (rr << 6) | (t4 ^ (rr & 7));
      wA[0][sidx] = ga[n];
      wA[1][sidx] = gb[n];
    }
    __syncthreads();

    const float4* ra4 = wA[0] + (r << 6);
    const float4* rb4 = wA[1] + (r << 6);
    float arr = 0.0f, aii = 0.0f;
#pragma unroll 8
    for (int t4 = 0; t4 < 64; t4++) {
      float4 tv = tb4[t4];        // broadcast within 16-lane b-group
      int s = t4 ^ c;
      float4 va = ra4[s];
      float4 vb = rb4[s];
      arr += tv.x * va.x + tv.y * va.y + tv.z * va.z + tv.w * va.w;
      aii += tv.x * vb.x + tv.y * vb.y + tv.z * vb.z + tv.w * vb.w;
    }
    if (pass) { o2r = arr; o2i = aii; } else { o1r = arr; o1i = aii; }
    __syncthreads();  // protect wA before restage / exit
  }

  tw1[(size_t)b * NROWS + row0 + r] = make_float2(o1r, o1i);
  tw2[(size_t)b * NROWS + row0 + r] = make_float2(o2r, o2i);
}

// ---------------------------------------------------------------------------
// K3: spectral mixing over input channels.
// ---------------------------------------------------------------------------
__global__ __launch_bounds__(256) void k3_mix(const float2* __restrict__ Xf,
                                              const float2* __restrict__ tw1,
                                              const float2* __restrict__ tw2,
                                              float2* __restrict__ ftT,
                                              float2* __restrict__ ftB) {
  const int n = blockIdx.x * 256 + threadIdx.x;
  const int xy = n & 255;
  const int ov = n >> 8;
  const int v = ov % 3;
  const int o = (ov / 3) & 7;
  const int b = n / (OC * NV * 256);

  float tr = 0.0f, ti2 = 0.0f, br = 0.0f, bi = 0.0f;
#pragma unroll
  for (int i = 0; i < IC; i++) {
    const float2 xt = Xf[(size_t)(((b * IC + i) * NV + v) << 9) + xy];
    const float2 xb = Xf[(size_t)(((b * IC + i) * NV + v) << 9) + 256 + xy];
    const int r = ((i * OC + o) * NV + v) * 256 + xy;
    float2 u1 = tw1[(size_t)b * NROWS + r];
    float2 u2 = tw2[(size_t)b * NROWS + r];
    tr += xt.x * u1.x - xt.y * u1.y;
    ti2 += xt.x * u1.y + xt.y * u1.x;
    br += xb.x * u2.x - xb.y * u2.y;
    bi += xb.x * u2.y + xb.y * u2.x;
  }
  const int nout = ((b * OC + o) * NV + v) * 256 + xy;
  ftT[nout] = make_float2(tr, ti2);
  ftB[nout] = make_float2(br, bi);
}

// ---------------------------------------------------------------------------
// K4a: G[img][ky][h] = sum_row ft[row][ky] e^{+2pi i kx_row h/256}. grid=384.
// ---------------------------------------------------------------------------
__global__ __launch_bounds__(256) void k4a_hdft(const float2* __restrict__ ftT,
                                                const float2* __restrict__ ftB,
                                                float2* __restrict__ G) {
  __shared__ float2 tbl[256];
  __shared__ float2 ftL[512];
  const int tid = threadIdx.x;
  const int img = blockIdx.x;
  {
    float s, c;
    sincosf((float)tid * (TWO_PI / 256.0f), &s, &c);
    tbl[tid] = make_float2(c, s);
    ftL[tid] = ftT[(size_t)img * 256 + tid];
    ftL[256 + tid] = ftB[(size_t)img * 256 + tid];
  }
  __syncthreads();

  const int h = tid;
  float gr[16], gi[16];
#pragma unroll
  for (int ky = 0; ky < 16; ky++) { gr[ky] = 0.0f; gi[ky] = 0.0f; }
  for (int row = 0; row < 32; row++) {
    int kxv = (row < 16) ? row : (224 + row);
    float2 e = tbl[(kxv * h) & 255];
#pragma unroll
    for (int ky = 0; ky < 16; ky++) {
      float2 f = ftL[row * 16 + ky];
      gr[ky] += f.x * e.x - f.y * e.y;
      gi[ky] += f.x * e.y + f.y * e.x;
    }
  }
  float2* Gi = G + (size_t)img * 4096;
#pragma unroll
  for (int ky = 0; ky < 16; ky++) Gi[ky * 256 + h] = make_float2(gr[ky], gi[ky]);
}

// ---------------------------------------------------------------------------
// K4b: out[h][w] = sum_ky Re(P[ky][w] * G[ky][h]). grid = 384*8.
// ---------------------------------------------------------------------------
__global__ __launch_bounds__(256) void k4b_wdft(const float2* __restrict__ G,
                                                float* __restrict__ out) {
  __shared__ float2 tbl[256];
  __shared__ float2 PL[16 * 256];
  __shared__ float2 gt[512];
  const int tid = threadIdx.x;
  const int img = blockIdx.x >> 3;
  const int h0 = (blockIdx.x & 7) * 32;
  {
    float s, c;
    sincosf((float)tid * (TWO_PI / 256.0f), &s, &c);
    tbl[tid] = make_float2(c, s);
  }
  __syncthreads();
  for (int n = tid; n < 4096; n += 256) {
    int ky = n >> 8, w = n & 255;
    float2 e = tbl[(ky * w) & 255];
    float sc = (ky == 0) ? (1.0f / 65536.0f) : (2.0f / 65536.0f);
    PL[n] = make_float2(e.x * sc, e.y * sc);
  }
  const float2* Gi = G + (size_t)img * 4096;
  for (int n = tid; n < 512; n += 256) {
    int ky = n >> 5, hh = n & 31;
    gt[n] = Gi[ky * 256 + h0 + hh];
  }
  __syncthreads();

  const int w0 = tid & 63;
  const int hq = tid >> 6;
  float acc[8][4];
#pragma unroll
  for (int a = 0; a < 8; a++)
#pragma unroll
    for (int j = 0; j < 4; j++) acc[a][j] = 0.0f;

#pragma unroll 4
  for (int ky = 0; ky < 16; ky++) {
    float2 p0 = PL[ky * 256 + w0];
    float2 p1 = PL[ky * 256 + w0 + 64];
    float2 p2 = PL[ky * 256 + w0 + 128];
    float2 p3 = PL[ky * 256 + w0 + 192];
#pragma unroll
    for (int a = 0; a < 8; a++) {
      float2 g = gt[ky * 32 + hq * 8 + a];
      acc[a][0] += g.x * p0.x - g.y * p0.y;
      acc[a][1] += g.x * p1.x - g.y * p1.y;
      acc[a][2] += g.x * p2.x - g.y * p2.y;
      acc[a][3] += g.x * p3.x - g.y * p3.y;
    }
  }
  float* obase = out + (size_t)img * 65536 + (size_t)(h0 + hq * 8) * 256;
#pragma unroll
  for (int a = 0; a < 8; a++) {
#pragma unroll
    for (int j = 0; j < 4; j++) obase[a * 256 + w0 + 64 * j] = acc[a][j];
  }
}

// ---------------------------------------------------------------------------
extern "C" void kernel_launch(void* const* d_in, const int* in_sizes, int n_in,
                              void* d_out, int out_size, void* d_ws, size_t ws_size,
                              hipStream_t stream) {
  const float* t = (const float*)d_in[0];
  const float* x = (const float*)d_in[1];
  const float* w1r = (const float*)d_in[2];
  const float* w1i = (const float*)d_in[3];
  const float* w2r = (const float*)d_in[4];
  const float* w2i = (const float*)d_in[5];
  float* out = (float*)d_out;

  float2* R1 = (float2*)d_ws;
  float2* y = R1;
  float2* tw1 = R1;
  float2* tw2 = R1 + 786432;
  float2* G = R1;
  float2* Xf = R1 + 1671168;
  float2* ftT = Xf + 196608;
  float2* ftB = ftT + 98304;

  k1a_rowdft<<<NIMG_IN * 2, 256, 0, stream>>>(x, y);
  k1b_coldft<<<NIMG_IN, 256, 0, stream>>>(y, Xf);
  k2_tw<<<NROWS / 16, 256, 0, stream>>>(t, w1r, w1i, w2r, w2i, tw1, tw2);
  k3_mix<<<(BB * OC * NV * 256) / 256, 256, 0, stream>>>(Xf, tw1, tw2, ftT, ftB);
  k4a_hdft<<<NIMG_OUT, 256, 0, stream>>>(ftT, ftB, G);
  k4b_wdft<<<NIMG_OUT * 8, 256, 0, stream>>>(G, out);
}

// Round 2
// 426.786 us; speedup vs baseline: 1.0990x; 1.0971x over previous
//
#include <hip/hip_runtime.h>

// Sizes
#define BB 16
#define IC 8
#define OC 8
#define NV 3
#define M1 16
#define M2 16
#define HH 256
#define WW 256
#define NIMG_IN  (BB*IC*NV)        // 384
#define NIMG_OUT (BB*OC*NV)        // 384
#define NROWS    (IC*OC*NV*M1*M2)  // 49152
#define TWO_PI 6.28318530717958647692f

// ---------------------------------------------------------------------------
// K1a: row DFT. grid = 768. blocks [0,384) = kx 0..8, [384,768) = kx 9..16
// (384 apart -> same XCD -> shared L2 for the image double-read).
// block 256 = (col2 0..127, hq 0..1). Each thread: 2 columns (float2 loads),
// 128 rows, 9 kx accumulators as 18 NAMED float2 (36 floats -> guaranteed
// VGPR allocation; round-0/1 array form overflowed the RF: VGPR_Count 56/84
// < 72 live accumulators, VALUBusy stuck at 22%). 4-row rotating prefetch.
// Twiddles via wave-uniform LDS broadcast. One-round LDS reduction over hq.
// y[img][kx][w] = sum_h e^{-2pi i kx h/256} x[h][w], kx in 0..16.
// ---------------------------------------------------------------------------
#define STEPJ(J, E, XV)                                   \
  ar##J.x = fmaf((E).x, (XV).x, ar##J.x);                 \
  ar##J.y = fmaf((E).x, (XV).y, ar##J.y);                 \
  ai##J.x = fmaf(-(E).y, (XV).x, ai##J.x);                \
  ai##J.y = fmaf(-(E).y, (XV).y, ai##J.y);

#define ROW(XV, H) {                                      \
  int m_ = (kbase * (H)) & 255;                           \
  float2 e_;                                              \
  e_ = tbl[m_]; STEPJ(0, e_, XV) m_ = (m_ + (H)) & 255;   \
  e_ = tbl[m_]; STEPJ(1, e_, XV) m_ = (m_ + (H)) & 255;   \
  e_ = tbl[m_]; STEPJ(2, e_, XV) m_ = (m_ + (H)) & 255;   \
  e_ = tbl[m_]; STEPJ(3, e_, XV) m_ = (m_ + (H)) & 255;   \
  e_ = tbl[m_]; STEPJ(4, e_, XV) m_ = (m_ + (H)) & 255;   \
  e_ = tbl[m_]; STEPJ(5, e_, XV) m_ = (m_ + (H)) & 255;   \
  e_ = tbl[m_]; STEPJ(6, e_, XV) m_ = (m_ + (H)) & 255;   \
  e_ = tbl[m_]; STEPJ(7, e_, XV) m_ = (m_ + (H)) & 255;   \
  e_ = tbl[m_]; STEPJ(8, e_, XV)                          \
}

#define STORJ(J) p[(J)*4+0]=ar##J.x; p[(J)*4+1]=ar##J.y; p[(J)*4+2]=ai##J.x; p[(J)*4+3]=ai##J.y;
#define LOADJ(J) ar##J.x+=p[(J)*4+0]; ar##J.y+=p[(J)*4+1]; ai##J.x+=p[(J)*4+2]; ai##J.y+=p[(J)*4+3];
#define OUTJ(J)  yo4[(kbase+(J))*128 + col2] = make_float4(ar##J.x, ai##J.x, ar##J.y, ai##J.y);

__global__ __launch_bounds__(256, 3) void k1a_rowdft(const float* __restrict__ x,
                                                     float2* __restrict__ y) {
  __shared__ float2 tbl[256];
  __shared__ float red[128][37];  // 18.5 KB; stride 37 -> 2 lanes/bank (free)
  const int tid = threadIdx.x;
  const int bid = blockIdx.x;
  const int half = (bid >= 384) ? 1 : 0;
  const int img = bid - half * 384;
  const int kbase = half ? 9 : 0;
  const int kcount = half ? 8 : 9;
  {
    float s, c;
    sincosf((float)tid * (TWO_PI / 256.0f), &s, &c);
    tbl[tid] = make_float2(c, s);
  }
  __syncthreads();

  const int col2 = tid & 127;
  const int hq = tid >> 7;
  const int hbase = hq * 128;
  const float2* xp = (const float2*)(x + (size_t)img * 65536) + col2;

  float2 ar0 = {0,0}, ar1 = {0,0}, ar2 = {0,0}, ar3 = {0,0}, ar4 = {0,0},
         ar5 = {0,0}, ar6 = {0,0}, ar7 = {0,0}, ar8 = {0,0};
  float2 ai0 = {0,0}, ai1 = {0,0}, ai2 = {0,0}, ai3 = {0,0}, ai4 = {0,0},
         ai5 = {0,0}, ai6 = {0,0}, ai7 = {0,0}, ai8 = {0,0};

  // 4-row rotating prefetch (4 outstanding VMEM/wave)
  float2 c0 = xp[(size_t)(hbase + 0) * 128];
  float2 c1 = xp[(size_t)(hbase + 1) * 128];
  float2 c2 = xp[(size_t)(hbase + 2) * 128];
  float2 c3 = xp[(size_t)(hbase + 3) * 128];

  for (int hi = 0; hi < 128; hi += 4) {
    const int hn = (hbase + hi + 4) & 255;  // wraps in-image; dead on last iter
    float2 n0 = xp[(size_t)(hn + 0) * 128];
    float2 n1 = xp[(size_t)(hn + 1) * 128];
    float2 n2 = xp[(size_t)(hn + 2) * 128];
    float2 n3 = xp[(size_t)(hn + 3) * 128];

    const int h = hbase + hi;
    ROW(c0, h + 0)
    ROW(c1, h + 1)
    ROW(c2, h + 2)
    ROW(c3, h + 3)

    c0 = n0; c1 = n1; c2 = n2; c3 = n3;
  }

  // reduce over hq (2 partials): hq=1 stores, hq=0 adds + writes
  if (hq) {
    float* p = &red[col2][0];
    STORJ(0) STORJ(1) STORJ(2) STORJ(3) STORJ(4) STORJ(5) STORJ(6) STORJ(7) STORJ(8)
  }
  __syncthreads();
  if (!hq) {
    const float* p = &red[col2][0];
    LOADJ(0) LOADJ(1) LOADJ(2) LOADJ(3) LOADJ(4) LOADJ(5) LOADJ(6) LOADJ(7) LOADJ(8)
    float4* yo4 = (float4*)(y + (size_t)img * 4352);
    OUTJ(0) OUTJ(1) OUTJ(2) OUTJ(3) OUTJ(4) OUTJ(5) OUTJ(6) OUTJ(7)
    if (kcount == 9) { OUTJ(8) }
  }
}

// ---------------------------------------------------------------------------
// K1b: column DFT over retained ky modes. grid = 384 (img).
// ---------------------------------------------------------------------------
__global__ __launch_bounds__(256) void k1b_coldft(const float2* __restrict__ y,
                                                  float2* __restrict__ Xf) {
  __shared__ float2 tbl[256];
  __shared__ float2 yb[17 * 257];
  const int tid = threadIdx.x;
  const int img = blockIdx.x;
  {
    float s, c;
    sincosf((float)tid * (TWO_PI / 256.0f), &s, &c);
    tbl[tid] = make_float2(c, s);
  }
  const float2* yg = y + (size_t)img * 4352;
  for (int n = tid; n < 4352; n += 256) {
    int kx = n >> 8, w = n & 255;
    yb[kx * 257 + w] = yg[n];
  }
  __syncthreads();

  float2* XfImg = Xf + (size_t)img * 512;
  for (int n = tid; n < 512; n += 256) {
    int row = n >> 4, ky = n & 15;
    int kxl = (row < 16) ? row : (32 - row);
    float sgn = (row < 16) ? 1.0f : -1.0f;
    float Xr = 0.0f, Xi = 0.0f;
    int m = 0;
    for (int w2 = 0; w2 < 256; w2++) {
      float2 yv = yb[kxl * 257 + w2];
      float2 e = tbl[m];
      m = (m + ky) & 255;
      float yy = yv.y * sgn;
      Xr += yv.x * e.x + yy * e.y;
      Xi += yy * e.x - yv.x * e.y;
    }
    XfImg[n] = make_float2(Xr, Xi);
  }
}

// ---------------------------------------------------------------------------
// K2: tw[b][row] = sum_t t[b][t] * w[row][t].  grid = 3072 (16 rows/block).
// Coalesced float4 staging of w tiles into LDS (XOR swizzle, conflict-free),
// thread = (b, r) computes via broadcast t + swizzled w reads.
// Two passes: (w1r,w1i) then (w2r,w2i); LDS = 16.6 + 32 KB.
// ---------------------------------------------------------------------------
__global__ __launch_bounds__(256) void k2_tw(const float* __restrict__ t,
                                             const float* __restrict__ w1r,
                                             const float* __restrict__ w1i,
                                             const float* __restrict__ w2r,
                                             const float* __restrict__ w2i,
                                             float2* __restrict__ tw1,
                                             float2* __restrict__ tw2) {
  __shared__ float tL[16 * 260];          // [b][260], padded (65 float4 pitch)
  __shared__ float4 wA[2][16 * 64];       // [arr][row][t4 ^ (row&7)]
  const int tid = threadIdx.x;
  const int row0 = blockIdx.x * 16;
  const int b = tid >> 4;
  const int r = tid & 15;
  const int c = r & 7;

  // stage t (once): 1024 float4, coalesced
  {
    const float4* tg = (const float4*)t;
    float4* ts = (float4*)tL;
    for (int n = tid; n < 1024; n += 256) ts[(n >> 6) * 65 + (n & 63)] = tg[n];
  }

  float o1r, o1i, o2r, o2i;
  const float4* tb4 = (const float4*)tL + b * 65;

  for (int pass = 0; pass < 2; pass++) {
    const float* wa = pass ? w2r : w1r;
    const float* wb = pass ? w2i : w1i;
    // stage w pair, coalesced with XOR swizzle
    const float4* ga = (const float4*)(wa + (size_t)row0 * 256);
    const float4* gb = (const float4*)(wb + (size_t)row0 * 256);
    for (int n = tid; n < 1024; n += 256) {
      int rr = n >> 6, t4 = n & 63;
      int sidx = (rr << 6) | (t4 ^ (rr & 7));
      wA[0][sidx] = ga[n];
      wA[1][sidx] = gb[n];
    }
    __syncthreads();

    const float4* ra4 = wA[0] + (r << 6);
    const float4* rb4 = wA[1] + (r << 6);
    float arr = 0.0f, aii = 0.0f;
#pragma unroll 8
    for (int t4 = 0; t4 < 64; t4++) {
      float4 tv = tb4[t4];        // broadcast within 16-lane b-group
      int s = t4 ^ c;
      float4 va = ra4[s];
      float4 vb = rb4[s];
      arr += tv.x * va.x + tv.y * va.y + tv.z * va.z + tv.w * va.w;
      aii += tv.x * vb.x + tv.y * vb.y + tv.z * vb.z + tv.w * vb.w;
    }
    if (pass) { o2r = arr; o2i = aii; } else { o1r = arr; o1i = aii; }
    __syncthreads();  // protect wA before restage / exit
  }

  tw1[(size_t)b * NROWS + row0 + r] = make_float2(o1r, o1i);
  tw2[(size_t)b * NROWS + row0 + r] = make_float2(o2r, o2i);
}

// ---------------------------------------------------------------------------
// K3: spectral mixing over input channels.
// ---------------------------------------------------------------------------
__global__ __launch_bounds__(256) void k3_mix(const float2* __restrict__ Xf,
                                              const float2* __restrict__ tw1,
                                              const float2* __restrict__ tw2,
                                              float2* __restrict__ ftT,
                                              float2* __restrict__ ftB) {
  const int n = blockIdx.x * 256 + threadIdx.x;
  const int xy = n & 255;
  const int ov = n >> 8;
  const int v = ov % 3;
  const int o = (ov / 3) & 7;
  const int b = n / (OC * NV * 256);

  float tr = 0.0f, ti2 = 0.0f, br = 0.0f, bi = 0.0f;
#pragma unroll
  for (int i = 0; i < IC; i++) {
    const float2 xt = Xf[(size_t)(((b * IC + i) * NV + v) << 9) + xy];
    const float2 xb = Xf[(size_t)(((b * IC + i) * NV + v) << 9) + 256 + xy];
    const int r = ((i * OC + o) * NV + v) * 256 + xy;
    float2 u1 = tw1[(size_t)b * NROWS + r];
    float2 u2 = tw2[(size_t)b * NROWS + r];
    tr += xt.x * u1.x - xt.y * u1.y;
    ti2 += xt.x * u1.y + xt.y * u1.x;
    br += xb.x * u2.x - xb.y * u2.y;
    bi += xb.x * u2.y + xb.y * u2.x;
  }
  const int nout = ((b * OC + o) * NV + v) * 256 + xy;
  ftT[nout] = make_float2(tr, ti2);
  ftB[nout] = make_float2(br, bi);
}

// ---------------------------------------------------------------------------
// K4a: G[img][ky][h] = sum_row ft[row][ky] e^{+2pi i kx_row h/256}. grid=384.
// ---------------------------------------------------------------------------
__global__ __launch_bounds__(256) void k4a_hdft(const float2* __restrict__ ftT,
                                                const float2* __restrict__ ftB,
                                                float2* __restrict__ G) {
  __shared__ float2 tbl[256];
  __shared__ float2 ftL[512];
  const int tid = threadIdx.x;
  const int img = blockIdx.x;
  {
    float s, c;
    sincosf((float)tid * (TWO_PI / 256.0f), &s, &c);
    tbl[tid] = make_float2(c, s);
    ftL[tid] = ftT[(size_t)img * 256 + tid];
    ftL[256 + tid] = ftB[(size_t)img * 256 + tid];
  }
  __syncthreads();

  const int h = tid;
  float gr[16], gi[16];
#pragma unroll
  for (int ky = 0; ky < 16; ky++) { gr[ky] = 0.0f; gi[ky] = 0.0f; }
  for (int row = 0; row < 32; row++) {
    int kxv = (row < 16) ? row : (224 + row);
    float2 e = tbl[(kxv * h) & 255];
#pragma unroll
    for (int ky = 0; ky < 16; ky++) {
      float2 f = ftL[row * 16 + ky];
      gr[ky] += f.x * e.x - f.y * e.y;
      gi[ky] += f.x * e.y + f.y * e.x;
    }
  }
  float2* Gi = G + (size_t)img * 4096;
#pragma unroll
  for (int ky = 0; ky < 16; ky++) Gi[ky * 256 + h] = make_float2(gr[ky], gi[ky]);
}

// ---------------------------------------------------------------------------
// K4b: out[h][w] = sum_ky Re(P[ky][w] * G[ky][h]). grid = 384*8.
// ---------------------------------------------------------------------------
__global__ __launch_bounds__(256) void k4b_wdft(const float2* __restrict__ G,
                                                float* __restrict__ out) {
  __shared__ float2 tbl[256];
  __shared__ float2 PL[16 * 256];
  __shared__ float2 gt[512];
  const int tid = threadIdx.x;
  const int img = blockIdx.x >> 3;
  const int h0 = (blockIdx.x & 7) * 32;
  {
    float s, c;
    sincosf((float)tid * (TWO_PI / 256.0f), &s, &c);
    tbl[tid] = make_float2(c, s);
  }
  __syncthreads();
  for (int n = tid; n < 4096; n += 256) {
    int ky = n >> 8, w = n & 255;
    float2 e = tbl[(ky * w) & 255];
    float sc = (ky == 0) ? (1.0f / 65536.0f) : (2.0f / 65536.0f);
    PL[n] = make_float2(e.x * sc, e.y * sc);
  }
  const float2* Gi = G + (size_t)img * 4096;
  for (int n = tid; n < 512; n += 256) {
    int ky = n >> 5, hh = n & 31;
    gt[n] = Gi[ky * 256 + h0 + hh];
  }
  __syncthreads();

  const int w0 = tid & 63;
  const int hq = tid >> 6;
  float acc[8][4];
#pragma unroll
  for (int a = 0; a < 8; a++)
#pragma unroll
    for (int j = 0; j < 4; j++) acc[a][j] = 0.0f;

#pragma unroll 4
  for (int ky = 0; ky < 16; ky++) {
    float2 p0 = PL[ky * 256 + w0];
    float2 p1 = PL[ky * 256 + w0 + 64];
    float2 p2 = PL[ky * 256 + w0 + 128];
    float2 p3 = PL[ky * 256 + w0 + 192];
#pragma unroll
    for (int a = 0; a < 8; a++) {
      float2 g = gt[ky * 32 + hq * 8 + a];
      acc[a][0] += g.x * p0.x - g.y * p0.y;
      acc[a][1] += g.x * p1.x - g.y * p1.y;
      acc[a][2] += g.x * p2.x - g.y * p2.y;
      acc[a][3] += g.x * p3.x - g.y * p3.y;
    }
  }
  float* obase = out + (size_t)img * 65536 + (size_t)(h0 + hq * 8) * 256;
#pragma unroll
  for (int a = 0; a < 8; a++) {
#pragma unroll
    for (int j = 0; j < 4; j++) obase[a * 256 + w0 + 64 * j] = acc[a][j];
  }
}

// ---------------------------------------------------------------------------
extern "C" void kernel_launch(void* const* d_in, const int* in_sizes, int n_in,
                              void* d_out, int out_size, void* d_ws, size_t ws_size,
                              hipStream_t stream) {
  const float* t = (const float*)d_in[0];
  const float* x = (const float*)d_in[1];
  const float* w1r = (const float*)d_in[2];
  const float* w1i = (const float*)d_in[3];
  const float* w2r = (const float*)d_in[4];
  const float* w2i = (const float*)d_in[5];
  float* out = (float*)d_out;

  float2* R1 = (float2*)d_ws;
  float2* y = R1;
  float2* tw1 = R1;
  float2* tw2 = R1 + 786432;
  float2* G = R1;
  float2* Xf = R1 + 1671168;
  float2* ftT = Xf + 196608;
  float2* ftB = ftT + 98304;

  k1a_rowdft<<<NIMG_IN * 2, 256, 0, stream>>>(x, y);
  k1b_coldft<<<NIMG_IN, 256, 0, stream>>>(y, Xf);
  k2_tw<<<NROWS / 16, 256, 0, stream>>>(t, w1r, w1i, w2r, w2i, tw1, tw2);
  k3_mix<<<(BB * OC * NV * 256) / 256, 256, 0, stream>>>(Xf, tw1, tw2, ftT, ftB);
  k4a_hdft<<<NIMG_OUT, 256, 0, stream>>>(ftT, ftB, G);
  k4b_wdft<<<NIMG_OUT * 8, 256, 0, stream>>>(G, out);
}